// Round 5
// baseline (619.064 us; speedup 1.0000x reference)
//
#include <hip/hip_runtime.h>

// Flash-attention fwd, B=4 H=16 S=2048 D=128, fp32 in/out, bf16 MFMA compute.
// Round 5: single-barrier K-loop restructure.
//  (a) global_load_lds width=16 double-buffered staging: DMA tile kt+1 issued
//      at TOP of iteration kt, barrier at END drains a long-landed queue.
//      One barrier per tile, no staging VGPRs, no staging LDS-write issue.
//  (b) BQ=128: 2 m-tiles per wave; K/V fragment reads (B-operands) shared
//      across m-tiles -> LDS fragment traffic per unit work halved.
//  (c) P region PLD=64 + XOR swizzle (blk^ (row&7)): writes 2-way (free),
//      A-frag reads single b128 at 8-dw/bank optimum. One region per wave,
//      reused m0->m1 (lgkm-serialized).
//  LDS = 2*16K (K) + 2*16K (V) + 8K (P) = 72KB -> 2 blocks/CU.
//  Prepass (round 4) unchanged; fallback = round-3 kernel.

#define S_LEN 2048
#define HD 128
#define BQ 128
#define BK 64
#define NT (S_LEN / BK)
#define TILE_ELEMS (BK * HD)   // 8192 bf16 = 16KB per tile image

typedef __attribute__((ext_vector_type(8))) short bf16x8;
typedef __attribute__((ext_vector_type(4))) float f32x4;
typedef __attribute__((ext_vector_type(4))) short s16x4;

#if __has_builtin(__builtin_amdgcn_exp2f)
#define EXP2F(x) __builtin_amdgcn_exp2f(x)
#else
#define EXP2F(x) exp2f(x)
#endif

#define GAS __attribute__((address_space(1)))
#define LAS __attribute__((address_space(3)))

static __device__ __forceinline__ void glds16(const void* g, void* l) {
    __builtin_amdgcn_global_load_lds((const GAS unsigned int*)g,
                                     (LAS unsigned int*)l, 16, 0, 0);
}

static __device__ __forceinline__ unsigned short f2bf(float f) {
    unsigned int u = __builtin_bit_cast(unsigned int, f);
    u += 0x7fffu + ((u >> 16) & 1u);   // round-to-nearest-even
    return (unsigned short)(u >> 16);
}

// ---------------- prepass: build bf16 tile images (unchanged) ----------------
__global__ __launch_bounds__(256, 2)
void preconv_kernel(const float* __restrict__ kg0, const float* __restrict__ vg0,
                    unsigned short* __restrict__ kws, unsigned short* __restrict__ vws)
{
    __shared__ unsigned short vt[TILE_ELEMS];
    const int tid = threadIdx.x;
    const int bh  = blockIdx.x;
    const int kt  = blockIdx.y;
    const float* kg = kg0 + ((size_t)bh * S_LEN + (size_t)kt * BK) * HD;
    const float* vg = vg0 + ((size_t)bh * S_LEN + (size_t)kt * BK) * HD;
    unsigned short* kimg = kws + ((size_t)bh * NT + kt) * TILE_ELEMS;
    unsigned short* vimg = vws + ((size_t)bh * NT + kt) * TILE_ELEMS;

    // K image: chunk c -> row r=c>>4, physical block pblk=c&15,
    // logical block b = (pblk&8)|((pblk&7)^(r&7))  (involution)
    #pragma unroll
    for (int i = 0; i < 4; ++i) {
        const int c = i * 256 + tid;
        const int r = c >> 4, pblk = c & 15;
        const int b = (pblk & 8) | ((pblk & 7) ^ (r & 7));
        const f32x4 lo = *(const f32x4*)(kg + r * HD + b * 8);
        const f32x4 hi = *(const f32x4*)(kg + r * HD + b * 8 + 4);
        bf16x8 o;
        #pragma unroll
        for (int j = 0; j < 4; ++j) {
            o[j]     = (short)f2bf(lo[j]);
            o[j + 4] = (short)f2bf(hi[j]);
        }
        *(bf16x8*)(kimg + (size_t)c * 8) = o;
    }

    // V^T image via LDS: in-register 8x4 transpose into swizzled layout.
    const int rr = tid >> 5, cc = tid & 31;
    f32x4 vr[8];
    #pragma unroll
    for (int it = 0; it < 8; ++it)
        vr[it] = *(const f32x4*)(vg + (size_t)(rr * 8 + it) * HD + cc * 4);
    #pragma unroll
    for (int i = 0; i < 4; ++i) {
        bf16x8 col;
        #pragma unroll
        for (int it = 0; it < 8; ++it)
            col[it] = (short)f2bf(vr[it][i]);
        const int d = cc * 4 + i;
        const int pblk = rr ^ (d & 7);
        *(bf16x8*)&vt[d * 64 + pblk * 8] = col;
    }
    __syncthreads();
    #pragma unroll
    for (int i = 0; i < 4; ++i) {
        const int c = i * 256 + tid;
        *(bf16x8*)(vimg + (size_t)c * 8) = *(const bf16x8*)&vt[c * 8];
    }
}

// ---------------- main flash kernel ----------------
__global__ __launch_bounds__(256, 2)
void fattn_main(const float* __restrict__ qg0,
                const unsigned short* __restrict__ kws,
                const unsigned short* __restrict__ vws,
                const float* __restrict__ maskg, float* __restrict__ outg0)
{
    __shared__ short k_lds[2][TILE_ELEMS];   // K tile images, double-buffered
    __shared__ short vt_lds[2][TILE_ELEMS];  // V^T tile images, double-buffered
    __shared__ short p_lds[4][16 * 64];      // per-wave P tile, swizzled

    const int tid  = threadIdx.x;
    const int wave = tid >> 6;
    const int lane = tid & 63;
    const int quad = lane >> 4;
    const int l16  = lane & 15;

    const int bh = blockIdx.x;
    const int q0 = blockIdx.y * BQ;

    const float* qg = qg0 + (size_t)bh * S_LEN * HD;
    const unsigned short* kimg0 = kws + (size_t)bh * NT * TILE_ELEMS;
    const unsigned short* vimg0 = vws + (size_t)bh * NT * TILE_ELEMS;
    float* outg = outg0 + (size_t)bh * S_LEN * HD;

    // Q A-fragments for both m-tiles: m-rows = q0 + m*64 + wave*16 + l16
    bf16x8 qf[2][4];
    #pragma unroll
    for (int m = 0; m < 2; ++m) {
        const float* qrow = qg + (size_t)(q0 + m * 64 + wave * 16 + l16) * HD + quad * 8;
        #pragma unroll
        for (int ks = 0; ks < 4; ++ks) {
            const f32x4 a = *(const f32x4*)(qrow + ks * 32);
            const f32x4 b = *(const f32x4*)(qrow + ks * 32 + 4);
            #pragma unroll
            for (int j = 0; j < 4; ++j) {
                qf[m][ks][j]     = (short)f2bf(a[j]);
                qf[m][ks][j + 4] = (short)f2bf(b[j]);
            }
        }
    }

    float l_run[2][4] = {{0.f,0.f,0.f,0.f},{0.f,0.f,0.f,0.f}};
    f32x4 oacc[2][8];
    #pragma unroll
    for (int m = 0; m < 2; ++m)
        #pragma unroll
        for (int d = 0; d < 8; ++d) oacc[m][d] = (f32x4){0.f, 0.f, 0.f, 0.f};

    const float C1    = 0.088388347648318447f * 1.4426950408889634f; // scale*log2e
    const float LOG2E = 1.4426950408889634f;
    const float* mrow0 = maskg + (size_t)(q0 + wave * 16 + quad * 4) * S_LEN + l16;
    const float* mrow1 = mrow0 + (size_t)64 * S_LEN;

    short* const pw = p_lds[wave];
    const int wb = wave * 64;               // this wave's chunk base for DMA

    // ---- prologue: DMA tile 0 into buffer 0; prefetch mask tile 0 ----
    #pragma unroll
    for (int i = 0; i < 4; ++i) {
        const int c = i * 256 + wb;
        glds16(kimg0 + (size_t)(c + lane) * 8, &k_lds[0][c * 8]);
        glds16(vimg0 + (size_t)(c + lane) * 8, &vt_lds[0][c * 8]);
    }
    float mp2[2][4][4];
    #pragma unroll
    for (int nt = 0; nt < 4; ++nt)
        #pragma unroll
        for (int r = 0; r < 4; ++r) {
            mp2[0][nt][r] = mrow0[(size_t)r * S_LEN + nt * 16] * LOG2E;
            mp2[1][nt][r] = mrow1[(size_t)r * S_LEN + nt * 16] * LOG2E;
        }
    __syncthreads();   // drains prologue DMA

    for (int kt = 0; kt < NT; ++kt) {
        const int cur = kt & 1, nxt = cur ^ 1;
        const int nbt = (kt + 1 < NT) ? kt + 1 : 0;   // wrap: harmless dummy
        const short* kcur = k_lds[cur];
        const short* vcur = vt_lds[cur];

        // ---- (a) DMA tile kt+1 into the other buffer (drained by end barrier) ----
        {
            const unsigned short* kin = kimg0 + (size_t)nbt * TILE_ELEMS;
            const unsigned short* vin = vimg0 + (size_t)nbt * TILE_ELEMS;
            #pragma unroll
            for (int i = 0; i < 4; ++i) {
                const int c = i * 256 + wb;
                glds16(kin + (size_t)(c + lane) * 8, &k_lds[nxt][c * 8]);
                glds16(vin + (size_t)(c + lane) * 8, &vt_lds[nxt][c * 8]);
            }
        }

        // ---- (b) QK both m-tiles (K frags shared); fused softmax+P-write for m0 ----
        float pl0[4] = {0.f, 0.f, 0.f, 0.f};
        f32x4 sf1[4];
        #pragma unroll
        for (int nt = 0; nt < 4; ++nt) {
            f32x4 a0 = (f32x4){0.f,0.f,0.f,0.f}, a1 = (f32x4){0.f,0.f,0.f,0.f};
            const int row = nt * 16 + l16;
            #pragma unroll
            for (int ks = 0; ks < 4; ++ks) {
                const int b  = ks * 4 + quad;
                const int pb = (b & 8) | ((b & 7) ^ (row & 7));
                const bf16x8 kf = *(const bf16x8*)&kcur[row * 128 + pb * 8];
                a0 = __builtin_amdgcn_mfma_f32_16x16x32_bf16(qf[0][ks], kf, a0, 0, 0, 0);
                a1 = __builtin_amdgcn_mfma_f32_16x16x32_bf16(qf[1][ks], kf, a1, 0, 0, 0);
            }
            sf1[nt] = a1;
            #pragma unroll
            for (int r = 0; r < 4; ++r) {
                const float p = EXP2F(fmaf(a0[r], C1, mp2[0][nt][r]));
                const int prow = quad * 4 + r;
                pw[prow * 64 + (((nt * 2 + (l16 >> 3)) ^ (prow & 7)) << 3) + (l16 & 7)]
                    = (short)f2bf(p);
                pl0[r] += p;
            }
        }
        // prefetch next mask tile, m0 half (mp2[0] last used above)
        #pragma unroll
        for (int nt = 0; nt < 4; ++nt)
            #pragma unroll
            for (int r = 0; r < 4; ++r)
                mp2[0][nt][r] = mrow0[(size_t)r * S_LEN + nbt * BK + nt * 16] * LOG2E;

        // ---- (c) reduce l for m0; read P0 A-frags (single b128 via swizzle) ----
        #pragma unroll
        for (int r = 0; r < 4; ++r) {
            pl0[r] += __shfl_xor(pl0[r], 1, 16);
            pl0[r] += __shfl_xor(pl0[r], 2, 16);
            pl0[r] += __shfl_xor(pl0[r], 4, 16);
            pl0[r] += __shfl_xor(pl0[r], 8, 16);
            l_run[0][r] += pl0[r];
        }
        bf16x8 pf0[2];
        #pragma unroll
        for (int ks = 0; ks < 2; ++ks)
            pf0[ks] = *(const bf16x8*)&pw[l16 * 64 + (((ks * 4 + quad) ^ (l16 & 7)) << 3)];

        // ---- (d) softmax + P roundtrip for m1 (same region, lgkm-serialized) ----
        float pl1[4] = {0.f, 0.f, 0.f, 0.f};
        #pragma unroll
        for (int nt = 0; nt < 4; ++nt)
            #pragma unroll
            for (int r = 0; r < 4; ++r) {
                const float p = EXP2F(fmaf(sf1[nt][r], C1, mp2[1][nt][r]));
                const int prow = quad * 4 + r;
                pw[prow * 64 + (((nt * 2 + (l16 >> 3)) ^ (prow & 7)) << 3) + (l16 & 7)]
                    = (short)f2bf(p);
                pl1[r] += p;
            }
        #pragma unroll
        for (int nt = 0; nt < 4; ++nt)
            #pragma unroll
            for (int r = 0; r < 4; ++r)
                mp2[1][nt][r] = mrow1[(size_t)r * S_LEN + nbt * BK + nt * 16] * LOG2E;
        #pragma unroll
        for (int r = 0; r < 4; ++r) {
            pl1[r] += __shfl_xor(pl1[r], 1, 16);
            pl1[r] += __shfl_xor(pl1[r], 2, 16);
            pl1[r] += __shfl_xor(pl1[r], 4, 16);
            pl1[r] += __shfl_xor(pl1[r], 8, 16);
            l_run[1][r] += pl1[r];
        }
        bf16x8 pf1[2];
        #pragma unroll
        for (int ks = 0; ks < 2; ++ks)
            pf1[ks] = *(const bf16x8*)&pw[l16 * 64 + (((ks * 4 + quad) ^ (l16 & 7)) << 3)];

        // ---- (e) O += P V, both m-tiles (V frags shared) ----
        #pragma unroll
        for (int dt = 0; dt < 8; ++dt) {
            const int drow = dt * 16 + l16;
            #pragma unroll
            for (int ks = 0; ks < 2; ++ks) {
                const int pblk = (ks * 4 + quad) ^ (drow & 7);
                const bf16x8 vf = *(const bf16x8*)&vcur[drow * 64 + pblk * 8];
                oacc[0][dt] = __builtin_amdgcn_mfma_f32_16x16x32_bf16(pf0[ks], vf, oacc[0][dt], 0, 0, 0);
                oacc[1][dt] = __builtin_amdgcn_mfma_f32_16x16x32_bf16(pf1[ks], vf, oacc[1][dt], 0, 0, 0);
            }
        }

        __syncthreads();   // single barrier: separates buf[cur] reads from next writes
    }

    // ---- epilogue: normalize and store ----
    #pragma unroll
    for (int m = 0; m < 2; ++m)
        #pragma unroll
        for (int r = 0; r < 4; ++r) {
            const float inv = 1.0f / l_run[m][r];
            float* orow = outg + (size_t)(q0 + m * 64 + wave * 16 + quad * 4 + r) * HD + l16;
            #pragma unroll
            for (int d = 0; d < 8; ++d)
                orow[d * 16] = oacc[m][d][r] * inv;
        }
}

// ---------------- fallback (round-3): inline conversion, no ws ----------------
#define KLD 136
#define VLD 72
#define FPLD 68

__global__ __launch_bounds__(256, 2)
void fattn_fallback(const float* __restrict__ qg0, const float* __restrict__ kg0,
                    const float* __restrict__ vg0, const float* __restrict__ maskg,
                    float* __restrict__ outg0)
{
    __shared__ short k_lds[BK * KLD];
    __shared__ short vt_lds[HD * VLD];
    __shared__ short p_lds[4 * 16 * FPLD];

    const int tid  = threadIdx.x;
    const int wave = tid >> 6;
    const int lane = tid & 63;
    const int quad = lane >> 4;
    const int l16  = lane & 15;

    const int bh = blockIdx.x;
    const int q0 = blockIdx.y * 64;

    const float* qg   = qg0 + (size_t)bh * S_LEN * HD;
    const float* kg   = kg0 + (size_t)bh * S_LEN * HD;
    const float* vg   = vg0 + (size_t)bh * S_LEN * HD;
    float*       outg = outg0 + (size_t)bh * S_LEN * HD;

    bf16x8 qf[4];
    {
        const float* qrow = qg + (size_t)(q0 + wave * 16 + l16) * HD + quad * 8;
        #pragma unroll
        for (int ks = 0; ks < 4; ++ks) {
            const f32x4 a = *(const f32x4*)(qrow + ks * 32);
            const f32x4 b = *(const f32x4*)(qrow + ks * 32 + 4);
            #pragma unroll
            for (int j = 0; j < 4; ++j) {
                qf[ks][j]     = (short)f2bf(a[j]);
                qf[ks][j + 4] = (short)f2bf(b[j]);
            }
        }
    }

    float m_run[4], l_run[4];
    f32x4 oacc[8];
    #pragma unroll
    for (int r = 0; r < 4; ++r) { m_run[r] = -3.0e38f; l_run[r] = 0.0f; }
    #pragma unroll
    for (int d = 0; d < 8; ++d) oacc[d] = (f32x4){0.f, 0.f, 0.f, 0.f};

    const float scale = 0.088388347648318447f;
    const float* mrow = maskg + (size_t)(q0 + wave * 16 + quad * 4) * S_LEN + l16;

    const int rr = tid >> 5;
    const int cc = tid & 31;
    short* const pw = &p_lds[wave * 16 * FPLD];

    f32x4 kpre[8], vpre[8];
    float mpre[4][4];
    #pragma unroll
    for (int it = 0; it < 8; ++it)
        kpre[it] = *(const f32x4*)(kg + (size_t)(rr + 8 * it) * HD + cc * 4);
    #pragma unroll
    for (int it = 0; it < 8; ++it)
        vpre[it] = *(const f32x4*)(vg + (size_t)(rr * 8 + it) * HD + cc * 4);
    #pragma unroll
    for (int nt = 0; nt < 4; ++nt)
        #pragma unroll
        for (int r = 0; r < 4; ++r)
            mpre[nt][r] = mrow[(size_t)r * S_LEN + nt * 16];

    for (int kt = 0; kt < NT; ++kt) {
        __syncthreads();
        #pragma unroll
        for (int it = 0; it < 8; ++it) {
            s16x4 kb4;
            kb4[0] = (short)f2bf(kpre[it][0]); kb4[1] = (short)f2bf(kpre[it][1]);
            kb4[2] = (short)f2bf(kpre[it][2]); kb4[3] = (short)f2bf(kpre[it][3]);
            *(s16x4*)&k_lds[(rr + 8 * it) * KLD + cc * 4] = kb4;
        }
        #pragma unroll
        for (int i = 0; i < 4; ++i) {
            bf16x8 col;
            #pragma unroll
            for (int it = 0; it < 8; ++it)
                col[it] = (short)f2bf(vpre[it][i]);
            const int d = cc * 4 + i;
            const int pblk = rr ^ (cc & 7);
            *(bf16x8*)&vt_lds[d * VLD + pblk * 8] = col;
        }
        __syncthreads();

        const int nb = (kt + 1 < NT) ? (kt + 1) * BK : 0;
        #pragma unroll
        for (int it = 0; it < 8; ++it)
            kpre[it] = *(const f32x4*)(kg + (size_t)(nb + rr + 8 * it) * HD + cc * 4);
        #pragma unroll
        for (int it = 0; it < 8; ++it)
            vpre[it] = *(const f32x4*)(vg + (size_t)(nb + rr * 8 + it) * HD + cc * 4);

        f32x4 sf[4];
        #pragma unroll
        for (int nt = 0; nt < 4; ++nt) {
            f32x4 acc = (f32x4){0.f, 0.f, 0.f, 0.f};
            #pragma unroll
            for (int ks = 0; ks < 4; ++ks) {
                const bf16x8 kf =
                    *(const bf16x8*)&k_lds[(nt * 16 + l16) * KLD + ks * 32 + quad * 8];
                acc = __builtin_amdgcn_mfma_f32_16x16x32_bf16(qf[ks], kf, acc, 0, 0, 0);
            }
            sf[nt] = acc;
        }

        float sv[4][4];
        float mx[4] = {-3.0e38f, -3.0e38f, -3.0e38f, -3.0e38f};
        #pragma unroll
        for (int nt = 0; nt < 4; ++nt)
            #pragma unroll
            for (int r = 0; r < 4; ++r) {
                const float s = sf[nt][r] * scale + mpre[nt][r];
                sv[nt][r] = s;
                mx[r] = fmaxf(mx[r], s);
            }
        #pragma unroll
        for (int nt = 0; nt < 4; ++nt)
            #pragma unroll
            for (int r = 0; r < 4; ++r)
                mpre[nt][r] = mrow[(size_t)r * S_LEN + nb + nt * 16];
        #pragma unroll
        for (int r = 0; r < 4; ++r) {
            mx[r] = fmaxf(mx[r], __shfl_xor(mx[r], 1, 16));
            mx[r] = fmaxf(mx[r], __shfl_xor(mx[r], 2, 16));
            mx[r] = fmaxf(mx[r], __shfl_xor(mx[r], 4, 16));
            mx[r] = fmaxf(mx[r], __shfl_xor(mx[r], 8, 16));
        }
        float alpha[4], pl[4];
        #pragma unroll
        for (int r = 0; r < 4; ++r) {
            const float mnew = fmaxf(m_run[r], mx[r]);
            alpha[r] = __expf(m_run[r] - mnew);
            m_run[r] = mnew;
            pl[r] = 0.f;
        }
        short pb[4][4];
        #pragma unroll
        for (int nt = 0; nt < 4; ++nt)
            #pragma unroll
            for (int r = 0; r < 4; ++r) {
                const float p = __expf(sv[nt][r] - m_run[r]);
                const unsigned short b = f2bf(p);
                pb[nt][r] = (short)b;
                pl[r] += __builtin_bit_cast(float, (unsigned int)b << 16);
            }
        #pragma unroll
        for (int r = 0; r < 4; ++r) {
            pl[r] += __shfl_xor(pl[r], 1, 16);
            pl[r] += __shfl_xor(pl[r], 2, 16);
            pl[r] += __shfl_xor(pl[r], 4, 16);
            pl[r] += __shfl_xor(pl[r], 8, 16);
            l_run[r] = l_run[r] * alpha[r] + pl[r];
        }
        #pragma unroll
        for (int d = 0; d < 8; ++d)
            #pragma unroll
            for (int r = 0; r < 4; ++r)
                oacc[d][r] *= alpha[r];

        #pragma unroll
        for (int nt = 0; nt < 4; ++nt)
            #pragma unroll
            for (int r = 0; r < 4; ++r)
                pw[(quad * 4 + r) * FPLD + nt * 16 + l16] = pb[nt][r];

        bf16x8 pf[2];
        #pragma unroll
        for (int ks = 0; ks < 2; ++ks) {
            const s16x4 lo = *(const s16x4*)&pw[l16 * FPLD + ks * 32 + quad * 8];
            const s16x4 hi = *(const s16x4*)&pw[l16 * FPLD + ks * 32 + quad * 8 + 4];
            pf[ks] = __builtin_shufflevector(lo, hi, 0, 1, 2, 3, 4, 5, 6, 7);
        }
        #pragma unroll
        for (int dt = 0; dt < 8; ++dt) {
            const int drow = dt * 16 + l16;
            const int tsw  = (drow >> 2) & 7;
            #pragma unroll
            for (int ks = 0; ks < 2; ++ks) {
                const bf16x8 vf =
                    *(const bf16x8*)&vt_lds[drow * VLD + (((4 * ks + quad) ^ tsw) * 8)];
                oacc[dt] = __builtin_amdgcn_mfma_f32_16x16x32_bf16(pf[ks], vf, oacc[dt], 0, 0, 0);
            }
        }
    }

    const int orow0 = q0 + wave * 16 + quad * 4;
    #pragma unroll
    for (int r = 0; r < 4; ++r) {
        const float inv = 1.0f / l_run[r];
        float* orow = outg + (size_t)(orow0 + r) * HD + l16;
        #pragma unroll
        for (int d = 0; d < 8; ++d)
            orow[d * 16] = oacc[d][r] * inv;
    }
}

extern "C" void kernel_launch(void* const* d_in, const int* in_sizes, int n_in,
                              void* d_out, int out_size, void* d_ws, size_t ws_size,
                              hipStream_t stream) {
    const float* q    = (const float*)d_in[0];
    const float* k    = (const float*)d_in[1];
    const float* v    = (const float*)d_in[2];
    const float* mask = (const float*)d_in[3];
    float* out = (float*)d_out;

    const size_t img_elems = (size_t)64 * NT * TILE_ELEMS;          // per tensor
    const size_t need = 2 * img_elems * sizeof(unsigned short);     // 64 MiB

    if (ws_size >= need) {
        unsigned short* kws = (unsigned short*)d_ws;
        unsigned short* vws = kws + img_elems;
        preconv_kernel<<<dim3(64, NT), 256, 0, stream>>>(k, v, kws, vws);
        fattn_main<<<dim3(64, S_LEN / BQ), 256, 0, stream>>>(q, kws, vws, mask, out);
    } else {
        fattn_fallback<<<dim3(64, S_LEN / 64), 256, 0, stream>>>(q, k, v, mask, out);
    }
}